// Round 4
// baseline (614.139 us; speedup 1.0000x reference)
//
#include <hip/hip_runtime.h>
#include <stdint.h>

#define B_ 16
#define C_ 512
#define T_ 4096
#define H_ 8
#define D_ 64
#define SCALE_ 0.125f
#define EPS_ 1e-5f

using ushortT = unsigned short;
using ushort8 = __attribute__((ext_vector_type(8))) unsigned short;
using short8  = __attribute__((ext_vector_type(8))) short;
using floatx4 = __attribute__((ext_vector_type(4))) float;

__device__ __forceinline__ float bf2f(ushortT u) {
  union { unsigned int i; float f; } x; x.i = ((unsigned int)u) << 16; return x.f;
}
__device__ __forceinline__ ushortT f2bf(float f) {
  union { float f; unsigned int i; } x; x.f = f;
  unsigned int r = x.i + 0x7fffu + ((x.i >> 16) & 1u);
  return (ushortT)(r >> 16);
}

// async 16B global->LDS (direct DMA). LDS dest is wave-uniform base + lane*16.
#define GLD16(gp, lp)                                                          \
  __builtin_amdgcn_global_load_lds(                                            \
      (const __attribute__((address_space(1))) unsigned int*)(gp),             \
      (__attribute__((address_space(3))) unsigned int*)(lp), 16, 0, 0)

// ---------------- fp32 -> bf16 convert (weights) ----------------
__global__ __launch_bounds__(256) void cvt_f32_bf16(const float* __restrict__ src,
                                                    ushortT* __restrict__ dst, int n4) {
  int i = blockIdx.x * 256 + threadIdx.x;
  if (i >= n4) return;
  floatx4 v = *(const floatx4*)(src + (size_t)i * 4);
  unsigned int p0 = (unsigned int)f2bf(v[0]) | ((unsigned int)f2bf(v[1]) << 16);
  unsigned int p1 = (unsigned int)f2bf(v[2]) | ((unsigned int)f2bf(v[3]) << 16);
  *(unsigned long long*)(dst + (size_t)i * 4) =
      (unsigned long long)p0 | ((unsigned long long)p1 << 32);
}

// ---------------- zero init ----------------
__global__ void zero_f32(float* p, int n4) {
  int i = blockIdx.x * 256 + threadIdx.x;
  if (i < n4) ((floatx4*)p)[i] = (floatx4){0.f, 0.f, 0.f, 0.f};
}

// ---------------- transpose x[b][c][t] (fp32) -> xT[b][t][c] (bf16) ----------------
__global__ __launch_bounds__(256) void transpose_x(const float* __restrict__ x,
                                                   ushortT* __restrict__ xT) {
  __shared__ ushortT tile[64][65];
  int b = blockIdx.z;
  int t0 = blockIdx.x * 64, c0 = blockIdx.y * 64;
  const float* xb = x + (size_t)b * C_ * T_;
  ushortT* xTb = xT + (size_t)b * T_ * C_;
  for (int i = threadIdx.x; i < 4096; i += 256) {
    int cc = i >> 6, tt = i & 63;
    tile[cc][tt] = f2bf(xb[(size_t)(c0 + cc) * T_ + t0 + tt]);
  }
  __syncthreads();
  for (int i = threadIdx.x; i < 4096; i += 256) {
    int tt = i >> 6, cc = i & 63;
    xTb[(size_t)(t0 + tt) * C_ + c0 + cc] = tile[cc][tt];
  }
}

// ---------------- merged QKV GEMM ----------------
// C_full[m][t] = sum_c Wqkv[m][c]*xT[t][c], M=1536, N=4096, K=512, per batch.
// grid (32, 12, 16), block 256. 128x128 tile, BK=32, 16x16x32 MFMA.
//   m0 <  512 : q rows   -> softmax over each 64-row head block (*SCALE_),
//               transposed write to qT[b][t][o] via XOR-swizzled LDS bounce.
//   512<=m0<1024 : k rows -> write exp(acc) bf16 to kv (defer-max: k~N(0,1),
//               exp<=~e^6; softmax normalizer applied later via ksum).
//   m0 >= 1024: v rows   -> plain bf16 to kv.
// Softmax layout proof (q): wave rows = wm + i*16+quad*4+r span exactly the 64 d
// of head (m0+wm)/64; for a fixed column (j,ln) the 64 values live in 16 regs
// (i,r) x 4 lanes {ln,ln+16,ln+32,ln+48} -> shfl_xor(16),shfl_xor(32) reduce.
// Bounce: write lds[t*64 + (o^((t&7)<<3))]; since the XOR only permutes whole
// 8-elem groups, readback of group g at row tt is contiguous at group g^(tt&7)
// -> single ds_read_b128, then coalesced 128B global strips of qT.
__global__ __launch_bounds__(256) void gemm_qkv(
    const ushortT* __restrict__ A,    // Wqkv bf16 [1536][512]
    const ushortT* __restrict__ Bt,   // xT bf16 [b][4096][512]
    ushortT* __restrict__ qT,         // [b][4096][512]
    ushortT* __restrict__ kvout) {    // [b][1024][4096]
  __shared__ ushortT lds[2 * 128 * 32];
  ushortT* As = lds;
  ushortT* Bs = lds + 128 * 32;
  // ---- XCD swizzle (bijective, nwg=6144 %8==0) ----
  unsigned int gx = gridDim.x, gy = gridDim.y;
  unsigned int nwg = gx * gy * gridDim.z;
  unsigned int lin = blockIdx.x + gx * (blockIdx.y + gy * blockIdx.z);
  unsigned int cpx = nwg >> 3;
  unsigned int wid = (lin & 7u) * cpx + (lin >> 3);
  unsigned int bx = wid % gx;
  unsigned int tmp = wid / gx;
  unsigned int by = tmp % gy;
  unsigned int bz = tmp / gy;

  const int b = bz;
  const ushortT* Bb = Bt + (size_t)b * (T_ * 512);
  const int m0 = by * 128, n0 = bx * 128;
  const int tid = threadIdx.x;
  const int w = tid >> 6, l = tid & 63;
  const int wm = (w >> 1) * 64, wn = (w & 1) * 64;
  const int quad = l >> 4, ln = l & 15;
  floatx4 acc[4][4];
#pragma unroll
  for (int i = 0; i < 4; i++)
#pragma unroll
    for (int j = 0; j < 4; j++) acc[i][j] = (floatx4){0.f, 0.f, 0.f, 0.f};

  for (int kb = 0; kb < 512; kb += 32) {
#pragma unroll
    for (int i = 0; i < 2; ++i) {
      int wci = i * 256 + (tid & 192);   // wave-uniform chunk base
      int ci  = wci + (tid & 63);        // this lane's chunk
      int row = ci >> 2, col = (ci & 3) << 3;
      GLD16(&A[(size_t)(m0 + row) * 512 + kb + col], &As[wci * 8]);
      GLD16(&Bb[(size_t)(n0 + row) * 512 + kb + col], &Bs[wci * 8]);
    }
    __syncthreads();
    short8 af[4], bfv[4];
#pragma unroll
    for (int i = 0; i < 4; i++) af[i] = *(const short8*)(&As[(wm + i * 16 + ln) * 32 + quad * 8]);
#pragma unroll
    for (int j = 0; j < 4; j++) bfv[j] = *(const short8*)(&Bs[(wn + j * 16 + ln) * 32 + quad * 8]);
#pragma unroll
    for (int i = 0; i < 4; i++)
#pragma unroll
      for (int j = 0; j < 4; j++)
        acc[i][j] = __builtin_amdgcn_mfma_f32_16x16x32_bf16(af[i], bfv[j], acc[i][j], 0, 0, 0);
    __syncthreads();
  }

  if (m0 < 512) {
    // ---- q: softmax over the wave's 64-row head, per column ----
#pragma unroll
    for (int j = 0; j < 4; j++) {
      float mx = -1e30f;
#pragma unroll
      for (int i = 0; i < 4; i++)
#pragma unroll
        for (int r = 0; r < 4; r++) mx = fmaxf(mx, acc[i][j][r]);
      mx = fmaxf(mx, __shfl_xor(mx, 16));
      mx = fmaxf(mx, __shfl_xor(mx, 32));
      float s = 0.f;
#pragma unroll
      for (int i = 0; i < 4; i++)
#pragma unroll
        for (int r = 0; r < 4; r++) {
          float e = expf(acc[i][j][r] - mx);
          acc[i][j][r] = e;
          s += e;
        }
      s += __shfl_xor(s, 16);
      s += __shfl_xor(s, 32);
      float inv = SCALE_ / s;
#pragma unroll
      for (int i = 0; i < 4; i++)
#pragma unroll
        for (int r = 0; r < 4; r++) acc[i][j][r] *= inv;
    }
    // ---- transposed store via XOR-swizzled LDS bounce, two 64-row halves ----
    ushortT* qb = qT + (size_t)b * T_ * 512;
#pragma unroll
    for (int half = 0; half < 2; ++half) {
      __syncthreads();
      if ((w >> 1) == half) {
#pragma unroll
        for (int i = 0; i < 4; i++)
#pragma unroll
          for (int r = 0; r < 4; r++) {
            int o = i * 16 + quad * 4 + r;
#pragma unroll
            for (int j = 0; j < 4; j++) {
              int t = wn + j * 16 + ln;
              lds[t * 64 + (o ^ ((t & 7) << 3))] = f2bf(acc[i][j][r]);
            }
          }
      }
      __syncthreads();
      int tt = tid >> 1;
#pragma unroll
      for (int c = 0; c < 4; ++c) {
        int g = (tid & 1) * 4 + c;
        short8 v = *(const short8*)(&lds[tt * 64 + ((g ^ (tt & 7)) * 8)]);
        *(short8*)(&qb[(size_t)(n0 + tt) * 512 + m0 + half * 64 + g * 8]) = v;
      }
    }
  } else {
    // ---- k (exp'd) / v (plain) -> kv[b][orow][t] ----
    const int isk = (m0 < 1024);
    ushortT* kvb = kvout + (size_t)b * (1024 * (size_t)T_);
#pragma unroll
    for (int i = 0; i < 4; i++)
#pragma unroll
      for (int r = 0; r < 4; r++) {
        int orow = m0 - 512 + wm + i * 16 + quad * 4 + r;
#pragma unroll
        for (int j = 0; j < 4; j++) {
          int col = n0 + wn + j * 16 + ln;
          float v = acc[i][j][r];
          if (isk) v = expf(v);
          kvb[(size_t)orow * T_ + col] = f2bf(v);
        }
      }
  }
}

// ---------------- bf16 GEMM: C[m][n] = sum_k A[m][k]*Bt[n][k] ----------------
// MODE 3: fp32 out + bias + fused GroupNorm stats. (Other modes unused.)
template <int MODE>
__global__ __launch_bounds__(256) void gemm_bt(
    const ushortT* __restrict__ A, const ushortT* __restrict__ Bt,
    void* __restrict__ Cc, const float* __restrict__ bias,
    float* __restrict__ stats,
    int K, int lda, int ldb, int ldc,
    unsigned long long bsA, unsigned long long bsB, unsigned long long bsC) {
  __shared__ ushortT As[128 * 32];
  __shared__ ushortT Bs[128 * 32];
  unsigned int gx = gridDim.x, gy = gridDim.y;
  unsigned int nwg = gx * gy * gridDim.z;
  unsigned int lin = blockIdx.x + gx * (blockIdx.y + gy * blockIdx.z);
  unsigned int cpx = nwg >> 3;
  unsigned int wid = (lin & 7u) * cpx + (lin >> 3);
  unsigned int bx = wid % gx;
  unsigned int tmp = wid / gx;
  unsigned int by = tmp % gy;
  unsigned int bz = tmp / gy;

  const int b = bz;
  A += (size_t)b * bsA; Bt += (size_t)b * bsB;
  const int m0 = by * 128, n0 = bx * 128;
  const int tid = threadIdx.x;
  const int w = tid >> 6, l = tid & 63;
  const int wm = (w >> 1) * 64, wn = (w & 1) * 64;
  const int quad = l >> 4, ln = l & 15;
  floatx4 acc[4][4];
#pragma unroll
  for (int i = 0; i < 4; i++)
#pragma unroll
    for (int j = 0; j < 4; j++) acc[i][j] = (floatx4){0.f, 0.f, 0.f, 0.f};

  for (int kb = 0; kb < K; kb += 32) {
#pragma unroll
    for (int i = 0; i < 2; ++i) {
      int wci = i * 256 + (tid & 192);
      int ci  = wci + (tid & 63);
      int row = ci >> 2, col = (ci & 3) << 3;
      GLD16(&A[(size_t)(m0 + row) * lda + kb + col], &As[wci * 8]);
      GLD16(&Bt[(size_t)(n0 + row) * ldb + kb + col], &Bs[wci * 8]);
    }
    __syncthreads();
    short8 af[4], bfv[4];
#pragma unroll
    for (int i = 0; i < 4; i++) af[i] = *(const short8*)(&As[(wm + i * 16 + ln) * 32 + quad * 8]);
#pragma unroll
    for (int j = 0; j < 4; j++) bfv[j] = *(const short8*)(&Bs[(wn + j * 16 + ln) * 32 + quad * 8]);
#pragma unroll
    for (int i = 0; i < 4; i++)
#pragma unroll
      for (int j = 0; j < 4; j++)
        acc[i][j] = __builtin_amdgcn_mfma_f32_16x16x32_bf16(af[i], bfv[j], acc[i][j], 0, 0, 0);
    __syncthreads();
  }

  {  // MODE == 3
    float* Co = (float*)Cc + (size_t)b * bsC;
    float s = 0.f, ss = 0.f;
#pragma unroll
    for (int i = 0; i < 4; i++)
#pragma unroll
      for (int r = 0; r < 4; r++) {
        int row = m0 + wm + i * 16 + quad * 4 + r;
        float bv = bias ? bias[row] : 0.f;
#pragma unroll
        for (int j = 0; j < 4; j++) {
          int col = n0 + wn + j * 16 + ln;
          float v = acc[i][j][r] + bv;
          Co[(size_t)row * ldc + col] = v;
          s += v; ss += v * v;
        }
      }
#pragma unroll
    for (int off = 1; off < 64; off <<= 1) {
      s += __shfl_xor(s, off);
      ss += __shfl_xor(ss, off);
    }
    __shared__ float rs[4], rss[4];
    if (l == 0) { rs[w] = s; rss[w] = ss; }
    __syncthreads();
    if (tid == 0) {
      atomicAdd(&stats[b * 2],     rs[0] + rs[1] + rs[2] + rs[3]);
      atomicAdd(&stats[b * 2 + 1], rss[0] + rss[1] + rss[2] + rss[3]);
    }
  }
}

// ---------------- context: ctRAW[b][h][e][d] += sum_t v[e][t]*ek[d][t] ----------------
// grid (16 slices, 8 h, 16 b), block 64 (one wave). K pre-exp'd by gemm_qkv ->
// pure dual-DMA + MFMA loop. ksum[b][h*64+d] = sum_t ek recovered from the
// B-fragments (each (row,col) covered exactly once per wave per tile).
__global__ __launch_bounds__(64) void context_kv(const ushortT* __restrict__ kv,
                                                 float* __restrict__ ksum,
                                                 float* __restrict__ ct) {
  __shared__ ushortT Vs[64 * 32];
  __shared__ ushortT Ks[64 * 32];
  const int slice = blockIdx.x, h = blockIdx.y, b = blockIdx.z;
  const int t0 = slice * 256;
  const ushortT* vrow = kv + ((size_t)b * 1024 + 512 + h * 64) * T_;
  const ushortT* krow = kv + ((size_t)b * 1024 + h * 64) * T_;
  const int tid = threadIdx.x, quad = tid >> 4, ln = tid & 15;
  float rsum[4] = {0.f, 0.f, 0.f, 0.f};
  floatx4 acc[4][4];
#pragma unroll
  for (int i = 0; i < 4; i++)
#pragma unroll
    for (int j = 0; j < 4; j++) acc[i][j] = (floatx4){0.f, 0.f, 0.f, 0.f};
  for (int kb = 0; kb < 256; kb += 32) {
#pragma unroll
    for (int i = 0; i < 4; ++i) {
      int ci = i * 64 + tid;
      int row = ci >> 2, col = (ci & 3) << 3;
      GLD16(&vrow[(size_t)row * T_ + t0 + kb + col], &Vs[i * 512]);
      GLD16(&krow[(size_t)row * T_ + t0 + kb + col], &Ks[i * 512]);
    }
    __syncthreads();
    short8 af[4], bfv[4];
#pragma unroll
    for (int i = 0; i < 4; i++) af[i] = *(const short8*)(&Vs[(i * 16 + ln) * 32 + quad * 8]);
#pragma unroll
    for (int j = 0; j < 4; j++) {
      bfv[j] = *(const short8*)(&Ks[(j * 16 + ln) * 32 + quad * 8]);
#pragma unroll
      for (int e = 0; e < 8; e++) rsum[j] += bf2f((ushortT)bfv[j][e]);
    }
#pragma unroll
    for (int i = 0; i < 4; i++)
#pragma unroll
      for (int j = 0; j < 4; j++)
        acc[i][j] = __builtin_amdgcn_mfma_f32_16x16x32_bf16(af[i], bfv[j], acc[i][j], 0, 0, 0);
    __syncthreads();
  }
  // ksum: rsum[j] is row (j*16+ln), cols quad*8..+7 over this slice -> reduce quads
  float* ks = ksum + (size_t)b * 512 + h * 64;
#pragma unroll
  for (int j = 0; j < 4; ++j) {
    float s = rsum[j];
    s += __shfl_xor(s, 16);
    s += __shfl_xor(s, 32);
    if (quad == 0) atomicAdd(&ks[j * 16 + ln], s);
  }
  float* ctbh = ct + (size_t)(b * 8 + h) * 4096;
#pragma unroll
  for (int i = 0; i < 4; i++)
#pragma unroll
    for (int r = 0; r < 4; r++) {
      int e = i * 16 + quad * 4 + r;
#pragma unroll
      for (int j = 0; j < 4; j++) {
        int d = j * 16 + ln;
        atomicAdd(&ctbh[e * 64 + d], acc[i][j][r]);
      }
    }
}

// ---------------- W2[b][c][h*64+d] = sum_e Wout[c][h*64+e] * ctRAW[b][h][e][d]/ksum[d] ----------------
__global__ __launch_bounds__(64) void ct_combine(const ushortT* __restrict__ Wobf,
                                                 const float* __restrict__ ct,
                                                 const float* __restrict__ ksum,
                                                 ushortT* __restrict__ W2) {
  __shared__ ushortT As[64 * 64];   // Wout tile [c][e]
  __shared__ float Cs[64 * 64];     // ct tile [e][d] fp32
  const int c0 = blockIdx.x * 64, h = blockIdx.y, b = blockIdx.z;
  const int tid = threadIdx.x, quad = tid >> 4, ln = tid & 15;
  const float* ctbh = ct + (size_t)(b * 8 + h) * 4096;
#pragma unroll
  for (int i = 0; i < 8; ++i) {
    int ci = i * 64 + tid;
    int row = ci >> 3, col = (ci & 7) << 3;
    *(uint4*)(&As[row * 64 + col]) = *(const uint4*)(&Wobf[(size_t)(c0 + row) * 512 + h * 64 + col]);
  }
#pragma unroll
  for (int i = 0; i < 16; ++i) {
    int off = (i * 64 + tid) * 4;
    *(floatx4*)(&Cs[off]) = *(const floatx4*)(&ctbh[off]);
  }
  const float* ks = ksum + (size_t)b * 512 + h * 64;
  float invd[4];
#pragma unroll
  for (int j = 0; j < 4; j++) invd[j] = 1.f / ks[j * 16 + ln];
  __syncthreads();
  floatx4 acc[4][4];
#pragma unroll
  for (int i = 0; i < 4; i++)
#pragma unroll
    for (int j = 0; j < 4; j++) acc[i][j] = (floatx4){0.f, 0.f, 0.f, 0.f};
#pragma unroll
  for (int kk = 0; kk < 2; ++kk) {
    short8 af[4], bfv[4];
#pragma unroll
    for (int i = 0; i < 4; i++) af[i] = *(const short8*)(&As[(i * 16 + ln) * 64 + kk * 32 + quad * 8]);
#pragma unroll
    for (int j = 0; j < 4; j++) {
#pragma unroll
      for (int e2 = 0; e2 < 8; ++e2)
        bfv[j][e2] = (short)f2bf(Cs[(kk * 32 + quad * 8 + e2) * 64 + j * 16 + ln] * invd[j]);
    }
#pragma unroll
    for (int i = 0; i < 4; i++)
#pragma unroll
      for (int j = 0; j < 4; j++)
        acc[i][j] = __builtin_amdgcn_mfma_f32_16x16x32_bf16(af[i], bfv[j], acc[i][j], 0, 0, 0);
  }
  ushortT* W2b = W2 + (size_t)b * 512 * 512;
#pragma unroll
  for (int i = 0; i < 4; i++)
#pragma unroll
    for (int r = 0; r < 4; r++) {
      int row = c0 + i * 16 + quad * 4 + r;
#pragma unroll
      for (int j = 0; j < 4; j++) {
        int col = h * 64 + j * 16 + ln;
        W2b[(size_t)row * 512 + col] = f2bf(acc[i][j][r]);
      }
    }
}

// ---------------- GroupNorm apply (in-place on fp32 d_out) ----------------
__global__ __launch_bounds__(256) void gn_apply(float* __restrict__ out,
                                                const float* __restrict__ stats,
                                                const float* __restrict__ gnw,
                                                const float* __restrict__ gnb) {
  int b = blockIdx.y;
  int i = blockIdx.x * 256 + threadIdx.x;
  const float invN = 1.f / (float)(C_ * T_);
  float mean = stats[b * 2] * invN;
  float var = stats[b * 2 + 1] * invN - mean * mean;
  float inv = rsqrtf(var + EPS_);
  int c = i >> 9;
  float wv = gnw[c] * inv, bv = gnb[c];
  float* p = out + (size_t)b * C_ * T_ + (size_t)i * 8;
  floatx4 v0 = *(const floatx4*)p;
  floatx4 v1 = *(const floatx4*)(p + 4);
#pragma unroll
  for (int j = 0; j < 4; j++) v0[j] = (v0[j] - mean) * wv + bv;
#pragma unroll
  for (int j = 0; j < 4; j++) v1[j] = (v1[j] - mean) * wv + bv;
  *(floatx4*)p = v0;
  *(floatx4*)(p + 4) = v1;
}

extern "C" void kernel_launch(void* const* d_in, const int* in_sizes, int n_in,
                              void* d_out, int out_size, void* d_ws, size_t ws_size,
                              hipStream_t stream) {
  (void)in_sizes; (void)n_in; (void)out_size; (void)ws_size;
  const float* x    = (const float*)d_in[0];
  const float* Wqkv = (const float*)d_in[1];
  const float* Wout = (const float*)d_in[2];
  const float* bout = (const float*)d_in[3];
  const float* gnw  = (const float*)d_in[4];
  const float* gnb  = (const float*)d_in[5];
  float* out = (float*)d_out;

  // ws layout (132 MB):
  //   xT    bf16 [b][t][512]      @ 0          (64 MB; dead after gemm_qkv ->
  //                                             first 32 KB = ksum fp32[16][512],
  //                                             @1MB = W2 bf16[16][512][512])
  //   qT    bf16 [b][t][512]      @ 64M        (64 MB; read by final GEMM)
  //   Wq_bf bf16 [1536][512]      @ 128M
  //   Wo_bf bf16 [512][512]       @ 129.5M
  //   ct    fp32 [16][8][64][64]  @ 130M
  //   stats fp32 [32]             @ 132M
  // kv bf16 [b][1024][t] (128 MB) lives in d_out, dead after context_kv.
  char* ws = (char*)d_ws;
  ushortT* xT   = (ushortT*)(ws);
  ushortT* qT   = (ushortT*)(ws + 67108864);
  ushortT* Wqbf = (ushortT*)(ws + 134217728);
  ushortT* Wobf = (ushortT*)(ws + 135790592);
  float*   ct   = (float*)(ws + 136314880);
  float* stats  = (float*)(ws + 138412032);
  float* ksum   = (float*)(ws);                 // aliases xT; written after xT dead
  ushortT* W2   = (ushortT*)(ws + 1048576);     // aliases xT+1MB; written after xT dead
  ushortT* kv   = (ushortT*)d_out;

  cvt_f32_bf16<<<768, 256, 0, stream>>>(Wqkv, Wqbf, 196608);
  cvt_f32_bf16<<<256, 256, 0, stream>>>(Wout, Wobf, 65536);
  zero_f32<<<513, 256, 0, stream>>>(ct, 131080);   // ct + stats

  transpose_x<<<dim3(64, 8, 16), 256, 0, stream>>>(x, xT);

  // merged QKV GEMM: q (softmax'd, transposed to qT) + k (exp'd) + v -> kv
  gemm_qkv<<<dim3(32, 12, 16), 256, 0, stream>>>(Wqbf, xT, qT, kv);

  // xT dead -> zero ksum (32 KB at ws[0:32K])
  zero_f32<<<8, 256, 0, stream>>>(ksum, 2048);

  context_kv<<<dim3(16, 8, 16), 64, 0, stream>>>(kv, ksum, ct);

  // W2[b] = Wout . (ct[b] * diag(1/ksum))
  ct_combine<<<dim3(8, 8, 16), 64, 0, stream>>>(Wobf, ct, ksum, W2);

  // out[b][c][t] = W2[b][c][:] . qT[b][t][:] + b_out[c], fused GN stats
  gemm_bt<3><<<dim3(32, 4, 16), 256, 0, stream>>>(
      W2, qT, out, bout, stats, 512, 512, 512, 4096,
      (unsigned long long)(512 * 512), (unsigned long long)(T_ * 512),
      (unsigned long long)(512 * T_));

  gn_apply<<<dim3(1024, 16), 256, 0, stream>>>(out, stats, gnw, gnb);
}

// Round 7
// 597.599 us; speedup vs baseline: 1.0277x; 1.0277x over previous
//
#include <hip/hip_runtime.h>
#include <stdint.h>

#define B_ 16
#define C_ 512
#define T_ 4096
#define H_ 8
#define D_ 64
#define SCALE_ 0.125f
#define EPS_ 1e-5f

using ushortT = unsigned short;
using ushort8 = __attribute__((ext_vector_type(8))) unsigned short;
using short8  = __attribute__((ext_vector_type(8))) short;
using floatx4 = __attribute__((ext_vector_type(4))) float;

__device__ __forceinline__ float bf2f(ushortT u) {
  union { unsigned int i; float f; } x; x.i = ((unsigned int)u) << 16; return x.f;
}
__device__ __forceinline__ ushortT f2bf(float f) {
  union { float f; unsigned int i; } x; x.f = f;
  unsigned int r = x.i + 0x7fffu + ((x.i >> 16) & 1u);
  return (ushortT)(r >> 16);
}

// async 16B global->LDS (direct DMA). LDS dest is wave-uniform base + lane*16.
#define GLD16(gp, lp)                                                          \
  __builtin_amdgcn_global_load_lds(                                            \
      (const __attribute__((address_space(1))) unsigned int*)(gp),             \
      (__attribute__((address_space(3))) unsigned int*)(lp), 16, 0, 0)

// ---------------- fp32 -> bf16 convert (weights) ----------------
__global__ __launch_bounds__(256) void cvt_f32_bf16(const float* __restrict__ src,
                                                    ushortT* __restrict__ dst, int n4) {
  int i = blockIdx.x * 256 + threadIdx.x;
  if (i >= n4) return;
  floatx4 v = *(const floatx4*)(src + (size_t)i * 4);
  unsigned int p0 = (unsigned int)f2bf(v[0]) | ((unsigned int)f2bf(v[1]) << 16);
  unsigned int p1 = (unsigned int)f2bf(v[2]) | ((unsigned int)f2bf(v[3]) << 16);
  *(unsigned long long*)(dst + (size_t)i * 4) =
      (unsigned long long)p0 | ((unsigned long long)p1 << 32);
}

// ---------------- zero init ----------------
__global__ void zero_f32(float* p, int n4) {
  int i = blockIdx.x * 256 + threadIdx.x;
  if (i < n4) ((floatx4*)p)[i] = (floatx4){0.f, 0.f, 0.f, 0.f};
}

// ---------------- transpose x[b][c][t] (fp32) -> xT[b][t][c] (bf16) ----------------
__global__ __launch_bounds__(256) void transpose_x(const float* __restrict__ x,
                                                   ushortT* __restrict__ xT) {
  __shared__ ushortT tile[64][65];
  int b = blockIdx.z;
  int t0 = blockIdx.x * 64, c0 = blockIdx.y * 64;
  const float* xb = x + (size_t)b * C_ * T_;
  ushortT* xTb = xT + (size_t)b * T_ * C_;
  for (int i = threadIdx.x; i < 4096; i += 256) {
    int cc = i >> 6, tt = i & 63;
    tile[cc][tt] = f2bf(xb[(size_t)(c0 + cc) * T_ + t0 + tt]);
  }
  __syncthreads();
  for (int i = threadIdx.x; i < 4096; i += 256) {
    int tt = i >> 6, cc = i & 63;
    xTb[(size_t)(t0 + tt) * C_ + c0 + cc] = tile[cc][tt];
  }
}

// ---------------- bf16 GEMM: C[m][n] = sum_k A[m][k]*Bt[n][k] ----------------
// grid: (N/128, M/128, batch), block 256. 128x128 tile, BK=32, 16x16x32 MFMA.
// Staging via global_load_lds width=16. XCD-aware bijective swizzle (nwg%8==0).
// MODE 2: bf16 out, fused softmax over each 64-col head block * SCALE_ (qT GEMM).
//         Wave w owns cols n0+(w&1)*64+j*16+ln = one aligned 64-wide head block;
//         for fixed (i,r) the row lives in one quad x 4 regs -> shfl_xor{1,2,4,8}.
// MODE 3: fp32 out + bias + fused GroupNorm stats (sum/sumsq atomicAdd per block).
// MODE 4: bf16 out; rows with m0<512 (k-rows of kv) get expf applied (defer-max:
//         k~N(0,1), exp<=~e^6; normalizer recovered as ksum in context_kv).
//         Block-uniform branch -> no divergence, no extra VGPR arrays.
template <int MODE>
__global__ __launch_bounds__(256) void gemm_bt(
    const ushortT* __restrict__ A, const ushortT* __restrict__ Bt,
    void* __restrict__ Cc, const float* __restrict__ bias,
    float* __restrict__ stats,
    int K, int lda, int ldb, int ldc,
    unsigned long long bsA, unsigned long long bsB, unsigned long long bsC) {
  __shared__ ushortT As[128 * 32];
  __shared__ ushortT Bs[128 * 32];
  // ---- XCD swizzle: hw linear id -> chunked work id ----
  unsigned int gx = gridDim.x, gy = gridDim.y;
  unsigned int nwg = gx * gy * gridDim.z;
  unsigned int lin = blockIdx.x + gx * (blockIdx.y + gy * blockIdx.z);
  unsigned int cpx = nwg >> 3;
  unsigned int wid = (lin & 7u) * cpx + (lin >> 3);
  unsigned int bx = wid % gx;
  unsigned int tmp = wid / gx;
  unsigned int by = tmp % gy;
  unsigned int bz = tmp / gy;

  const int b = bz;
  A += (size_t)b * bsA; Bt += (size_t)b * bsB;
  const int m0 = by * 128, n0 = bx * 128;
  const int tid = threadIdx.x;
  const int w = tid >> 6, l = tid & 63;
  const int wm = (w >> 1) * 64, wn = (w & 1) * 64;
  const int quad = l >> 4, ln = l & 15;
  floatx4 acc[4][4];
#pragma unroll
  for (int i = 0; i < 4; i++)
#pragma unroll
    for (int j = 0; j < 4; j++) acc[i][j] = (floatx4){0.f, 0.f, 0.f, 0.f};

  for (int kb = 0; kb < K; kb += 32) {
#pragma unroll
    for (int i = 0; i < 2; ++i) {
      int wci = i * 256 + (tid & 192);   // wave-uniform chunk base
      int ci  = wci + (tid & 63);        // this lane's chunk
      int row = ci >> 2, col = (ci & 3) << 3;
      GLD16(&A[(size_t)(m0 + row) * lda + kb + col], &As[wci * 8]);
      GLD16(&Bt[(size_t)(n0 + row) * ldb + kb + col], &Bs[wci * 8]);
    }
    __syncthreads();   // drains vmcnt (global_load_lds) before LDS reads
    short8 af[4], bfv[4];
#pragma unroll
    for (int i = 0; i < 4; i++) af[i] = *(const short8*)(&As[(wm + i * 16 + ln) * 32 + quad * 8]);
#pragma unroll
    for (int j = 0; j < 4; j++) bfv[j] = *(const short8*)(&Bs[(wn + j * 16 + ln) * 32 + quad * 8]);
#pragma unroll
    for (int i = 0; i < 4; i++)
#pragma unroll
      for (int j = 0; j < 4; j++)
        acc[i][j] = __builtin_amdgcn_mfma_f32_16x16x32_bf16(af[i], bfv[j], acc[i][j], 0, 0, 0);
    __syncthreads();
  }

  if constexpr (MODE == 4) {
    const bool isk = (m0 < 512);   // block-uniform
    ushortT* Co = (ushortT*)Cc + (size_t)b * bsC;
#pragma unroll
    for (int i = 0; i < 4; i++)
#pragma unroll
      for (int r = 0; r < 4; r++) {
        int row = m0 + wm + i * 16 + quad * 4 + r;
#pragma unroll
        for (int j = 0; j < 4; j++) {
          int col = n0 + wn + j * 16 + ln;
          float v = acc[i][j][r];
          if (isk) v = expf(v);
          Co[(size_t)row * ldc + col] = f2bf(v);
        }
      }
  } else if constexpr (MODE == 2) {
    // fused softmax over the wave's 64-col head block, then * SCALE_
    ushortT* Co = (ushortT*)Cc + (size_t)b * bsC;
#pragma unroll
    for (int i = 0; i < 4; i++)
#pragma unroll
      for (int r = 0; r < 4; r++) {
        float v0 = acc[i][0][r], v1 = acc[i][1][r], v2 = acc[i][2][r], v3 = acc[i][3][r];
        float mx = fmaxf(fmaxf(v0, v1), fmaxf(v2, v3));
#pragma unroll
        for (int off = 1; off < 16; off <<= 1) mx = fmaxf(mx, __shfl_xor(mx, off));
        float e0 = expf(v0 - mx), e1 = expf(v1 - mx);
        float e2 = expf(v2 - mx), e3 = expf(v3 - mx);
        float s = (e0 + e1) + (e2 + e3);
#pragma unroll
        for (int off = 1; off < 16; off <<= 1) s += __shfl_xor(s, off);
        float inv = SCALE_ / s;
        int row = m0 + wm + i * 16 + quad * 4 + r;
        size_t base = (size_t)row * ldc + n0 + wn + ln;
        Co[base +  0] = f2bf(e0 * inv);
        Co[base + 16] = f2bf(e1 * inv);
        Co[base + 32] = f2bf(e2 * inv);
        Co[base + 48] = f2bf(e3 * inv);
      }
  } else {  // MODE == 3: fp32 + bias + GN stats
    float* Co = (float*)Cc + (size_t)b * bsC;
    float s = 0.f, ss = 0.f;
#pragma unroll
    for (int i = 0; i < 4; i++)
#pragma unroll
      for (int r = 0; r < 4; r++) {
        int row = m0 + wm + i * 16 + quad * 4 + r;
        float bv = bias ? bias[row] : 0.f;
#pragma unroll
        for (int j = 0; j < 4; j++) {
          int col = n0 + wn + j * 16 + ln;
          float v = acc[i][j][r] + bv;
          Co[(size_t)row * ldc + col] = v;
          s += v; ss += v * v;
        }
      }
#pragma unroll
    for (int off = 1; off < 64; off <<= 1) {
      s += __shfl_xor(s, off);
      ss += __shfl_xor(ss, off);
    }
    __shared__ float rs[4], rss[4];
    if (l == 0) { rs[w] = s; rss[w] = ss; }
    __syncthreads();
    if (tid == 0) {
      atomicAdd(&stats[b * 2],     rs[0] + rs[1] + rs[2] + rs[3]);
      atomicAdd(&stats[b * 2 + 1], rss[0] + rss[1] + rss[2] + rss[3]);
    }
  }
}

// ---------------- context: ctRAW[b][h][e][d] += sum_t v[e][t]*ek[d][t] ----------------
// grid (16 slices, 8 h, 16 b), block 64 (one wave). K pre-exp'd by the kv GEMM ->
// pure dual-DMA + MFMA loop. ksum[b][h*64+d] = sum_t ek recovered from the
// B-fragments (each (row,col) covered exactly once per wave per tile).
__global__ __launch_bounds__(64) void context_kv(const ushortT* __restrict__ kv,
                                                 float* __restrict__ ksum,
                                                 float* __restrict__ ct) {
  __shared__ ushortT Vs[64 * 32];
  __shared__ ushortT Ks[64 * 32];
  const int slice = blockIdx.x, h = blockIdx.y, b = blockIdx.z;
  const int t0 = slice * 256;
  const ushortT* vrow = kv + ((size_t)b * 1024 + 512 + h * 64) * T_;
  const ushortT* krow = kv + ((size_t)b * 1024 + h * 64) * T_;
  const int tid = threadIdx.x, quad = tid >> 4, ln = tid & 15;
  float rsum[4] = {0.f, 0.f, 0.f, 0.f};
  floatx4 acc[4][4];
#pragma unroll
  for (int i = 0; i < 4; i++)
#pragma unroll
    for (int j = 0; j < 4; j++) acc[i][j] = (floatx4){0.f, 0.f, 0.f, 0.f};
  for (int kb = 0; kb < 256; kb += 32) {
#pragma unroll
    for (int i = 0; i < 4; ++i) {
      int ci = i * 64 + tid;
      int row = ci >> 2, col = (ci & 3) << 3;
      GLD16(&vrow[(size_t)row * T_ + t0 + kb + col], &Vs[i * 512]);
      GLD16(&krow[(size_t)row * T_ + t0 + kb + col], &Ks[i * 512]);
    }
    __syncthreads();
    short8 af[4], bfv[4];
#pragma unroll
    for (int i = 0; i < 4; i++) af[i] = *(const short8*)(&Vs[(i * 16 + ln) * 32 + quad * 8]);
#pragma unroll
    for (int j = 0; j < 4; j++) {
      bfv[j] = *(const short8*)(&Ks[(j * 16 + ln) * 32 + quad * 8]);
#pragma unroll
      for (int e = 0; e < 8; e++) rsum[j] += bf2f((ushortT)bfv[j][e]);
    }
#pragma unroll
    for (int i = 0; i < 4; i++)
#pragma unroll
      for (int j = 0; j < 4; j++)
        acc[i][j] = __builtin_amdgcn_mfma_f32_16x16x32_bf16(af[i], bfv[j], acc[i][j], 0, 0, 0);
    __syncthreads();
  }
  // ksum: rsum[j] is row (j*16+ln), cols quad*8..+7 of each tile -> reduce quads
  float* ks = ksum + (size_t)b * 512 + h * 64;
#pragma unroll
  for (int j = 0; j < 4; ++j) {
    float s = rsum[j];
    s += __shfl_xor(s, 16);
    s += __shfl_xor(s, 32);
    if (quad == 0) atomicAdd(&ks[j * 16 + ln], s);
  }
  float* ctbh = ct + (size_t)(b * 8 + h) * 4096;
#pragma unroll
  for (int i = 0; i < 4; i++)
#pragma unroll
    for (int r = 0; r < 4; r++) {
      int e = i * 16 + quad * 4 + r;
#pragma unroll
      for (int j = 0; j < 4; j++) {
        int d = j * 16 + ln;
        atomicAdd(&ctbh[e * 64 + d], acc[i][j][r]);
      }
    }
}

// ---------------- W2[b][c][h*64+d] = sum_e Wout[c][h*64+e] * ctRAW[b][h][e][d]/ksum[d] ----------------
// Reassociated attention tail: out = (Wout . ct) . q_sm (attn_out eliminated).
__global__ __launch_bounds__(64) void ct_combine(const ushortT* __restrict__ Wobf,
                                                 const float* __restrict__ ct,
                                                 const float* __restrict__ ksum,
                                                 ushortT* __restrict__ W2) {
  __shared__ ushortT As[64 * 64];   // Wout tile [c][e]
  __shared__ float Cs[64 * 64];     // ct tile [e][d] fp32
  const int c0 = blockIdx.x * 64, h = blockIdx.y, b = blockIdx.z;
  const int tid = threadIdx.x, quad = tid >> 4, ln = tid & 15;
  const float* ctbh = ct + (size_t)(b * 8 + h) * 4096;
#pragma unroll
  for (int i = 0; i < 8; ++i) {
    int ci = i * 64 + tid;
    int row = ci >> 3, col = (ci & 7) << 3;
    *(uint4*)(&As[row * 64 + col]) = *(const uint4*)(&Wobf[(size_t)(c0 + row) * 512 + h * 64 + col]);
  }
#pragma unroll
  for (int i = 0; i < 16; ++i) {
    int off = (i * 64 + tid) * 4;
    *(floatx4*)(&Cs[off]) = *(const floatx4*)(&ctbh[off]);
  }
  const float* ks = ksum + (size_t)b * 512 + h * 64;
  float invd[4];
#pragma unroll
  for (int j = 0; j < 4; j++) invd[j] = 1.f / ks[j * 16 + ln];
  __syncthreads();
  floatx4 acc[4][4];
#pragma unroll
  for (int i = 0; i < 4; i++)
#pragma unroll
    for (int j = 0; j < 4; j++) acc[i][j] = (floatx4){0.f, 0.f, 0.f, 0.f};
#pragma unroll
  for (int kk = 0; kk < 2; ++kk) {
    short8 af[4], bfv[4];
#pragma unroll
    for (int i = 0; i < 4; i++) af[i] = *(const short8*)(&As[(i * 16 + ln) * 64 + kk * 32 + quad * 8]);
#pragma unroll
    for (int j = 0; j < 4; j++) {
#pragma unroll
      for (int e2 = 0; e2 < 8; ++e2)
        bfv[j][e2] = (short)f2bf(Cs[(kk * 32 + quad * 8 + e2) * 64 + j * 16 + ln] * invd[j]);
    }
#pragma unroll
    for (int i = 0; i < 4; i++)
#pragma unroll
      for (int j = 0; j < 4; j++)
        acc[i][j] = __builtin_amdgcn_mfma_f32_16x16x32_bf16(af[i], bfv[j], acc[i][j], 0, 0, 0);
  }
  ushortT* W2b = W2 + (size_t)b * 512 * 512;
#pragma unroll
  for (int i = 0; i < 4; i++)
#pragma unroll
    for (int r = 0; r < 4; r++) {
      int row = c0 + i * 16 + quad * 4 + r;
#pragma unroll
      for (int j = 0; j < 4; j++) {
        int col = h * 64 + j * 16 + ln;
        W2b[(size_t)row * 512 + col] = f2bf(acc[i][j][r]);
      }
    }
}

// ---------------- GroupNorm apply (in-place on fp32 d_out) ----------------
__global__ __launch_bounds__(256) void gn_apply(float* __restrict__ out,
                                                const float* __restrict__ stats,
                                                const float* __restrict__ gnw,
                                                const float* __restrict__ gnb) {
  int b = blockIdx.y;
  int i = blockIdx.x * 256 + threadIdx.x;
  const float invN = 1.f / (float)(C_ * T_);
  float mean = stats[b * 2] * invN;
  float var = stats[b * 2 + 1] * invN - mean * mean;
  float inv = rsqrtf(var + EPS_);
  int c = i >> 9;
  float wv = gnw[c] * inv, bv = gnb[c];
  float* p = out + (size_t)b * C_ * T_ + (size_t)i * 8;
  floatx4 v0 = *(const floatx4*)p;
  floatx4 v1 = *(const floatx4*)(p + 4);
#pragma unroll
  for (int j = 0; j < 4; j++) v0[j] = (v0[j] - mean) * wv + bv;
#pragma unroll
  for (int j = 0; j < 4; j++) v1[j] = (v1[j] - mean) * wv + bv;
  *(floatx4*)p = v0;
  *(floatx4*)(p + 4) = v1;
}

extern "C" void kernel_launch(void* const* d_in, const int* in_sizes, int n_in,
                              void* d_out, int out_size, void* d_ws, size_t ws_size,
                              hipStream_t stream) {
  (void)in_sizes; (void)n_in; (void)out_size; (void)ws_size;
  const float* x    = (const float*)d_in[0];
  const float* Wqkv = (const float*)d_in[1];
  const float* Wout = (const float*)d_in[2];
  const float* bout = (const float*)d_in[3];
  const float* gnw  = (const float*)d_in[4];
  const float* gnb  = (const float*)d_in[5];
  float* out = (float*)d_out;

  // ws layout (132 MB):
  //   xT    bf16 [b][t][512]      @ 0          (64 MB; dead after the two QKV
  //                                             GEMMs -> first 32 KB = ksum
  //                                             fp32[16][512], @1MB = W2
  //                                             bf16[16][512][512] (8 MB))
  //   qT    bf16 [b][t][512]      @ 64M        (64 MB; read by final GEMM)
  //   Wq_bf bf16 [1536][512]      @ 128M
  //   Wo_bf bf16 [512][512]       @ 129.5M
  //   ct    fp32 [16][8][64][64]  @ 130M
  //   stats fp32 [32]             @ 132M
  // kv bf16 [b][1024][t] (128 MB) lives in d_out, dead after context_kv,
  // before the final out-projection GEMM overwrites d_out.
  char* ws = (char*)d_ws;
  ushortT* xT   = (ushortT*)(ws);
  ushortT* qT   = (ushortT*)(ws + 67108864);
  ushortT* Wqbf = (ushortT*)(ws + 134217728);
  ushortT* Wobf = (ushortT*)(ws + 135790592);
  float*   ct   = (float*)(ws + 136314880);
  float* stats  = (float*)(ws + 138412032);
  float* ksum   = (float*)(ws);                 // aliases xT; written after xT dead
  ushortT* W2   = (ushortT*)(ws + 1048576);     // aliases xT+1MB; written after xT dead
  ushortT* kv   = (ushortT*)d_out;

  cvt_f32_bf16<<<768, 256, 0, stream>>>(Wqkv, Wqbf, 196608);
  cvt_f32_bf16<<<256, 256, 0, stream>>>(Wout, Wobf, 65536);
  zero_f32<<<513, 256, 0, stream>>>(ct, 131080);   // ct + stats

  transpose_x<<<dim3(64, 8, 16), 256, 0, stream>>>(x, xT);

  // kv[b][o'][t] = W_qkv[512+o'][:] . xT[b][t][:]; k-rows (o'<512) exp'd
  gemm_bt<4><<<dim3(32, 8, 16), 256, 0, stream>>>(
      Wqbf + 512 * 512, xT, kv, nullptr, nullptr, 512, 512, 512, 4096,
      0ULL, (unsigned long long)(T_ * 512), (unsigned long long)(1024 * T_));

  // qT[b][t][o] = xT[b][t][:] . W_qkv[o][:]  + fused softmax over d (*SCALE)
  gemm_bt<2><<<dim3(4, 32, 16), 256, 0, stream>>>(
      xT, Wqbf, qT, nullptr, nullptr, 512, 512, 512, 512,
      (unsigned long long)(T_ * 512), 0ULL, (unsigned long long)(T_ * 512));

  // xT dead -> zero ksum (32 KB at ws[0:32K])
  zero_f32<<<8, 256, 0, stream>>>(ksum, 2048);

  context_kv<<<dim3(16, 8, 16), 64, 0, stream>>>(kv, ksum, ct);

  // W2[b] = Wout . (ct[b] * diag(1/ksum))
  ct_combine<<<dim3(8, 8, 16), 64, 0, stream>>>(Wobf, ct, ksum, W2);

  // out[b][c][t] = W2[b][c][:] . qT[b][t][:] + b_out[c], fused GN stats
  gemm_bt<3><<<dim3(32, 4, 16), 256, 0, stream>>>(
      W2, qT, out, bout, stats, 512, 512, 512, 4096,
      (unsigned long long)(512 * 512), (unsigned long long)(T_ * 512),
      (unsigned long long)(512 * T_));

  gn_apply<<<dim3(1024, 16), 256, 0, stream>>>(out, stats, gnw, gnb);
}

// Round 11
// 567.398 us; speedup vs baseline: 1.0824x; 1.0532x over previous
//
#include <hip/hip_runtime.h>
#include <stdint.h>

#define B_ 16
#define C_ 512
#define T_ 4096
#define H_ 8
#define D_ 64
#define SCALE_ 0.125f
#define EPS_ 1e-5f

using ushortT = unsigned short;
using ushort8 = __attribute__((ext_vector_type(8))) unsigned short;
using short8  = __attribute__((ext_vector_type(8))) short;
using floatx4 = __attribute__((ext_vector_type(4))) float;

__device__ __forceinline__ float bf2f(ushortT u) {
  union { unsigned int i; float f; } x; x.i = ((unsigned int)u) << 16; return x.f;
}
__device__ __forceinline__ ushortT f2bf(float f) {
  union { float f; unsigned int i; } x; x.f = f;
  unsigned int r = x.i + 0x7fffu + ((x.i >> 16) & 1u);
  return (ushortT)(r >> 16);
}

// async 16B global->LDS (direct DMA). LDS dest is wave-uniform base + lane*16.
#define GLD16(gp, lp)                                                          \
  __builtin_amdgcn_global_load_lds(                                            \
      (const __attribute__((address_space(1))) unsigned int*)(gp),             \
      (__attribute__((address_space(3))) unsigned int*)(lp), 16, 0, 0)

// ---------------- fp32 -> bf16 convert (weights) ----------------
__global__ __launch_bounds__(256) void cvt_f32_bf16(const float* __restrict__ src,
                                                    ushortT* __restrict__ dst, int n4) {
  int i = blockIdx.x * 256 + threadIdx.x;
  if (i >= n4) return;
  floatx4 v = *(const floatx4*)(src + (size_t)i * 4);
  unsigned int p0 = (unsigned int)f2bf(v[0]) | ((unsigned int)f2bf(v[1]) << 16);
  unsigned int p1 = (unsigned int)f2bf(v[2]) | ((unsigned int)f2bf(v[3]) << 16);
  *(unsigned long long*)(dst + (size_t)i * 4) =
      (unsigned long long)p0 | ((unsigned long long)p1 << 32);
}

// ---------------- zero init ----------------
__global__ void zero_f32(float* p, int n4) {
  int i = blockIdx.x * 256 + threadIdx.x;
  if (i < n4) ((floatx4*)p)[i] = (floatx4){0.f, 0.f, 0.f, 0.f};
}

// ---------------- transpose x[b][c][t] (fp32) -> xT[b][t][c] (bf16) ----------------
__global__ __launch_bounds__(256) void transpose_x(const float* __restrict__ x,
                                                   ushortT* __restrict__ xT) {
  __shared__ ushortT tile[64][65];
  int b = blockIdx.z;
  int t0 = blockIdx.x * 64, c0 = blockIdx.y * 64;
  const float* xb = x + (size_t)b * C_ * T_;
  ushortT* xTb = xT + (size_t)b * T_ * C_;
  for (int i = threadIdx.x; i < 4096; i += 256) {
    int cc = i >> 6, tt = i & 63;
    tile[cc][tt] = f2bf(xb[(size_t)(c0 + cc) * T_ + t0 + tt]);
  }
  __syncthreads();
  for (int i = threadIdx.x; i < 4096; i += 256) {
    int tt = i >> 6, cc = i & 63;
    xTb[(size_t)(t0 + tt) * C_ + c0 + cc] = tile[cc][tt];
  }
}

// ---------------- bf16 GEMM: C[m][n] = sum_k A[m][k]*Bt[n][k] ----------------
// grid: (N/128, M/128, batch), block 256. 128x128 tile, BK=64, 16x16x32 MFMA.
// BK=64: 8 barrier-drain pairs for K=512 (was 16), 32 MFMA per pair (was 16).
// LDS XOR swizzle (T2, gload_lds-legal form m173/m201): LDS chunk (row,c) holds
// global chunk (row, c^(row&7)); frag read uses chunk (kk*4+quad)^(ln&7).
// Every 8-lane issue group then covers 8 distinct 4-bank groups -> conflict-free
// (unswizzled BK=64 would be 16-way; measured 8.4M conflict cyc at BK=32).
// Global source stays coalesced (permutation within each row's 128B line).
// XCD-aware bijective swizzle (nwg%8==0 for all launches).
// MODE 2: bf16 out, fused softmax over each 64-col head block * SCALE_ (qT GEMM).
// MODE 3: fp32 out + bias + fused GroupNorm stats (atomicAdd per block).
// MODE 4: bf16 out; k-row blocks (m0<512) get expf applied (defer-max).
template <int MODE>
__global__ __launch_bounds__(256) void gemm_bt(
    const ushortT* __restrict__ A, const ushortT* __restrict__ Bt,
    void* __restrict__ Cc, const float* __restrict__ bias,
    float* __restrict__ stats,
    int K, int lda, int ldb, int ldc,
    unsigned long long bsA, unsigned long long bsB, unsigned long long bsC) {
  __shared__ ushortT As[128 * 64];
  __shared__ ushortT Bs[128 * 64];
  // ---- XCD swizzle: hw linear id -> chunked work id ----
  unsigned int gx = gridDim.x, gy = gridDim.y;
  unsigned int nwg = gx * gy * gridDim.z;
  unsigned int lin = blockIdx.x + gx * (blockIdx.y + gy * blockIdx.z);
  unsigned int cpx = nwg >> 3;
  unsigned int wid = (lin & 7u) * cpx + (lin >> 3);
  unsigned int bx = wid % gx;
  unsigned int tmp = wid / gx;
  unsigned int by = tmp % gy;
  unsigned int bz = tmp / gy;

  const int b = bz;
  A += (size_t)b * bsA; Bt += (size_t)b * bsB;
  const int m0 = by * 128, n0 = bx * 128;
  const int tid = threadIdx.x;
  const int w = tid >> 6, l = tid & 63;
  const int wm = (w >> 1) * 64, wn = (w & 1) * 64;
  const int quad = l >> 4, ln = l & 15;
  floatx4 acc[4][4];
#pragma unroll
  for (int i = 0; i < 4; i++)
#pragma unroll
    for (int j = 0; j < 4; j++) acc[i][j] = (floatx4){0.f, 0.f, 0.f, 0.f};

  for (int kb = 0; kb < K; kb += 64) {
#pragma unroll
    for (int i = 0; i < 4; ++i) {
      int wci = i * 256 + (tid & 192);   // wave-uniform chunk base
      int ci  = wci + (tid & 63);        // this lane's chunk (row, c)
      int row = ci >> 3;
      int scol = ((ci & 7) ^ (row & 7)) << 3;   // pre-swizzled global column
      GLD16(&A[(size_t)(m0 + row) * lda + kb + scol], &As[wci * 8]);
      GLD16(&Bt[(size_t)(n0 + row) * ldb + kb + scol], &Bs[wci * 8]);
    }
    __syncthreads();   // drains vmcnt (global_load_lds) before LDS reads
#pragma unroll
    for (int kk = 0; kk < 2; ++kk) {
      short8 af[4], bfv[4];
#pragma unroll
      for (int i = 0; i < 4; i++)
        af[i] = *(const short8*)(
            &As[(wm + i * 16 + ln) * 64 + (((kk * 4 + quad) ^ (ln & 7)) << 3)]);
#pragma unroll
      for (int j = 0; j < 4; j++)
        bfv[j] = *(const short8*)(
            &Bs[(wn + j * 16 + ln) * 64 + (((kk * 4 + quad) ^ (ln & 7)) << 3)]);
#pragma unroll
      for (int i = 0; i < 4; i++)
#pragma unroll
        for (int j = 0; j < 4; j++)
          acc[i][j] = __builtin_amdgcn_mfma_f32_16x16x32_bf16(af[i], bfv[j], acc[i][j], 0, 0, 0);
    }
    __syncthreads();
  }

  if constexpr (MODE == 4) {
    const bool isk = (m0 < 512);   // block-uniform
    ushortT* Co = (ushortT*)Cc + (size_t)b * bsC;
#pragma unroll
    for (int i = 0; i < 4; i++)
#pragma unroll
      for (int r = 0; r < 4; r++) {
        int row = m0 + wm + i * 16 + quad * 4 + r;
#pragma unroll
        for (int j = 0; j < 4; j++) {
          int col = n0 + wn + j * 16 + ln;
          float v = acc[i][j][r];
          if (isk) v = expf(v);
          Co[(size_t)row * ldc + col] = f2bf(v);
        }
      }
  } else if constexpr (MODE == 2) {
    // fused softmax over the wave's 64-col head block, then * SCALE_
    ushortT* Co = (ushortT*)Cc + (size_t)b * bsC;
#pragma unroll
    for (int i = 0; i < 4; i++)
#pragma unroll
      for (int r = 0; r < 4; r++) {
        float v0 = acc[i][0][r], v1 = acc[i][1][r], v2 = acc[i][2][r], v3 = acc[i][3][r];
        float mx = fmaxf(fmaxf(v0, v1), fmaxf(v2, v3));
#pragma unroll
        for (int off = 1; off < 16; off <<= 1) mx = fmaxf(mx, __shfl_xor(mx, off));
        float e0 = expf(v0 - mx), e1 = expf(v1 - mx);
        float e2 = expf(v2 - mx), e3 = expf(v3 - mx);
        float s = (e0 + e1) + (e2 + e3);
#pragma unroll
        for (int off = 1; off < 16; off <<= 1) s += __shfl_xor(s, off);
        float inv = SCALE_ / s;
        int row = m0 + wm + i * 16 + quad * 4 + r;
        size_t base = (size_t)row * ldc + n0 + wn + ln;
        Co[base +  0] = f2bf(e0 * inv);
        Co[base + 16] = f2bf(e1 * inv);
        Co[base + 32] = f2bf(e2 * inv);
        Co[base + 48] = f2bf(e3 * inv);
      }
  } else {  // MODE == 3: fp32 + bias + GN stats
    float* Co = (float*)Cc + (size_t)b * bsC;
    float s = 0.f, ss = 0.f;
#pragma unroll
    for (int i = 0; i < 4; i++)
#pragma unroll
      for (int r = 0; r < 4; r++) {
        int row = m0 + wm + i * 16 + quad * 4 + r;
        float bv = bias ? bias[row] : 0.f;
#pragma unroll
        for (int j = 0; j < 4; j++) {
          int col = n0 + wn + j * 16 + ln;
          float v = acc[i][j][r] + bv;
          Co[(size_t)row * ldc + col] = v;
          s += v; ss += v * v;
        }
      }
#pragma unroll
    for (int off = 1; off < 64; off <<= 1) {
      s += __shfl_xor(s, off);
      ss += __shfl_xor(ss, off);
    }
    __shared__ float rs[4], rss[4];
    if (l == 0) { rs[w] = s; rss[w] = ss; }
    __syncthreads();
    if (tid == 0) {
      atomicAdd(&stats[b * 2],     rs[0] + rs[1] + rs[2] + rs[3]);
      atomicAdd(&stats[b * 2 + 1], rss[0] + rss[1] + rss[2] + rss[3]);
    }
  }
}

// ---------------- context: ctRAW[b][h][e][d] += sum_t v[e][t]*ek[d][t] ----------------
// grid (16 slices, 8 h, 16 b), block 64 (one wave). K pre-exp'd by the kv GEMM ->
// pure dual-DMA + MFMA loop. ksum[b][h*64+d] = sum_t ek recovered from the
// B-fragments (each (row,col) covered exactly once per wave per tile).
__global__ __launch_bounds__(64) void context_kv(const ushortT* __restrict__ kv,
                                                 float* __restrict__ ksum,
                                                 float* __restrict__ ct) {
  __shared__ ushortT Vs[64 * 32];
  __shared__ ushortT Ks[64 * 32];
  const int slice = blockIdx.x, h = blockIdx.y, b = blockIdx.z;
  const int t0 = slice * 256;
  const ushortT* vrow = kv + ((size_t)b * 1024 + 512 + h * 64) * T_;
  const ushortT* krow = kv + ((size_t)b * 1024 + h * 64) * T_;
  const int tid = threadIdx.x, quad = tid >> 4, ln = tid & 15;
  float rsum[4] = {0.f, 0.f, 0.f, 0.f};
  floatx4 acc[4][4];
#pragma unroll
  for (int i = 0; i < 4; i++)
#pragma unroll
    for (int j = 0; j < 4; j++) acc[i][j] = (floatx4){0.f, 0.f, 0.f, 0.f};
  for (int kb = 0; kb < 256; kb += 32) {
#pragma unroll
    for (int i = 0; i < 4; ++i) {
      int ci = i * 64 + tid;
      int row = ci >> 2, col = (ci & 3) << 3;
      GLD16(&vrow[(size_t)row * T_ + t0 + kb + col], &Vs[i * 512]);
      GLD16(&krow[(size_t)row * T_ + t0 + kb + col], &Ks[i * 512]);
    }
    __syncthreads();
    short8 af[4], bfv[4];
#pragma unroll
    for (int i = 0; i < 4; i++) af[i] = *(const short8*)(&Vs[(i * 16 + ln) * 32 + quad * 8]);
#pragma unroll
    for (int j = 0; j < 4; j++) {
      bfv[j] = *(const short8*)(&Ks[(j * 16 + ln) * 32 + quad * 8]);
#pragma unroll
      for (int e = 0; e < 8; e++) rsum[j] += bf2f((ushortT)bfv[j][e]);
    }
#pragma unroll
    for (int i = 0; i < 4; i++)
#pragma unroll
      for (int j = 0; j < 4; j++)
        acc[i][j] = __builtin_amdgcn_mfma_f32_16x16x32_bf16(af[i], bfv[j], acc[i][j], 0, 0, 0);
    __syncthreads();
  }
  // ksum: rsum[j] is row (j*16+ln), cols quad*8..+7 of each tile -> reduce quads
  float* ks = ksum + (size_t)b * 512 + h * 64;
#pragma unroll
  for (int j = 0; j < 4; ++j) {
    float s = rsum[j];
    s += __shfl_xor(s, 16);
    s += __shfl_xor(s, 32);
    if (quad == 0) atomicAdd(&ks[j * 16 + ln], s);
  }
  float* ctbh = ct + (size_t)(b * 8 + h) * 4096;
#pragma unroll
  for (int i = 0; i < 4; i++)
#pragma unroll
    for (int r = 0; r < 4; r++) {
      int e = i * 16 + quad * 4 + r;
#pragma unroll
      for (int j = 0; j < 4; j++) {
        int d = j * 16 + ln;
        atomicAdd(&ctbh[e * 64 + d], acc[i][j][r]);
      }
    }
}

// ---------------- W2[b][c][h*64+d] = sum_e Wout[c][h*64+e] * ctRAW[b][h][e][d]/ksum[d] ----------------
// Reassociated attention tail: out = (Wout . ct) . q_sm (attn_out eliminated).
__global__ __launch_bounds__(64) void ct_combine(const ushortT* __restrict__ Wobf,
                                                 const float* __restrict__ ct,
                                                 const float* __restrict__ ksum,
                                                 ushortT* __restrict__ W2) {
  __shared__ ushortT As[64 * 64];   // Wout tile [c][e]
  __shared__ float Cs[64 * 64];     // ct tile [e][d] fp32
  const int c0 = blockIdx.x * 64, h = blockIdx.y, b = blockIdx.z;
  const int tid = threadIdx.x, quad = tid >> 4, ln = tid & 15;
  const float* ctbh = ct + (size_t)(b * 8 + h) * 4096;
#pragma unroll
  for (int i = 0; i < 8; ++i) {
    int ci = i * 64 + tid;
    int row = ci >> 3, col = (ci & 7) << 3;
    *(uint4*)(&As[row * 64 + col]) = *(const uint4*)(&Wobf[(size_t)(c0 + row) * 512 + h * 64 + col]);
  }
#pragma unroll
  for (int i = 0; i < 16; ++i) {
    int off = (i * 64 + tid) * 4;
    *(floatx4*)(&Cs[off]) = *(const floatx4*)(&ctbh[off]);
  }
  const float* ks = ksum + (size_t)b * 512 + h * 64;
  float invd[4];
#pragma unroll
  for (int j = 0; j < 4; j++) invd[j] = 1.f / ks[j * 16 + ln];
  __syncthreads();
  floatx4 acc[4][4];
#pragma unroll
  for (int i = 0; i < 4; i++)
#pragma unroll
    for (int j = 0; j < 4; j++) acc[i][j] = (floatx4){0.f, 0.f, 0.f, 0.f};
#pragma unroll
  for (int kk = 0; kk < 2; ++kk) {
    short8 af[4], bfv[4];
#pragma unroll
    for (int i = 0; i < 4; i++) af[i] = *(const short8*)(&As[(i * 16 + ln) * 64 + kk * 32 + quad * 8]);
#pragma unroll
    for (int j = 0; j < 4; j++) {
#pragma unroll
      for (int e2 = 0; e2 < 8; ++e2)
        bfv[j][e2] = (short)f2bf(Cs[(kk * 32 + quad * 8 + e2) * 64 + j * 16 + ln] * invd[j]);
    }
#pragma unroll
    for (int i = 0; i < 4; i++)
#pragma unroll
      for (int j = 0; j < 4; j++)
        acc[i][j] = __builtin_amdgcn_mfma_f32_16x16x32_bf16(af[i], bfv[j], acc[i][j], 0, 0, 0);
  }
  ushortT* W2b = W2 + (size_t)b * 512 * 512;
#pragma unroll
  for (int i = 0; i < 4; i++)
#pragma unroll
    for (int r = 0; r < 4; r++) {
      int row = c0 + i * 16 + quad * 4 + r;
#pragma unroll
      for (int j = 0; j < 4; j++) {
        int col = h * 64 + j * 16 + ln;
        W2b[(size_t)row * 512 + col] = f2bf(acc[i][j][r]);
      }
    }
}

// ---------------- GroupNorm apply (in-place on fp32 d_out) ----------------
__global__ __launch_bounds__(256) void gn_apply(float* __restrict__ out,
                                                const float* __restrict__ stats,
                                                const float* __restrict__ gnw,
                                                const float* __restrict__ gnb) {
  int b = blockIdx.y;
  int i = blockIdx.x * 256 + threadIdx.x;
  const float invN = 1.f / (float)(C_ * T_);
  float mean = stats[b * 2] * invN;
  float var = stats[b * 2 + 1] * invN - mean * mean;
  float inv = rsqrtf(var + EPS_);
  int c = i >> 9;
  float wv = gnw[c] * inv, bv = gnb[c];
  float* p = out + (size_t)b * C_ * T_ + (size_t)i * 8;
  floatx4 v0 = *(const floatx4*)p;
  floatx4 v1 = *(const floatx4*)(p + 4);
#pragma unroll
  for (int j = 0; j < 4; j++) v0[j] = (v0[j] - mean) * wv + bv;
#pragma unroll
  for (int j = 0; j < 4; j++) v1[j] = (v1[j] - mean) * wv + bv;
  *(floatx4*)p = v0;
  *(floatx4*)(p + 4) = v1;
}

extern "C" void kernel_launch(void* const* d_in, const int* in_sizes, int n_in,
                              void* d_out, int out_size, void* d_ws, size_t ws_size,
                              hipStream_t stream) {
  (void)in_sizes; (void)n_in; (void)out_size; (void)ws_size;
  const float* x    = (const float*)d_in[0];
  const float* Wqkv = (const float*)d_in[1];
  const float* Wout = (const float*)d_in[2];
  const float* bout = (const float*)d_in[3];
  const float* gnw  = (const float*)d_in[4];
  const float* gnb  = (const float*)d_in[5];
  float* out = (float*)d_out;

  // ws layout (132 MB):
  //   xT    bf16 [b][t][512]      @ 0          (64 MB; dead after the two QKV
  //                                             GEMMs -> first 32 KB = ksum
  //                                             fp32[16][512], @1MB = W2
  //                                             bf16[16][512][512] (8 MB))
  //   qT    bf16 [b][t][512]      @ 64M        (64 MB; read by final GEMM)
  //   Wq_bf bf16 [1536][512]      @ 128M
  //   Wo_bf bf16 [512][512]       @ 129.5M
  //   ct    fp32 [16][8][64][64]  @ 130M
  //   stats fp32 [32]             @ 132M
  // kv bf16 [b][1024][t] (128 MB) lives in d_out, dead after context_kv,
  // before the final out-projection GEMM overwrites d_out.
  char* ws = (char*)d_ws;
  ushortT* xT   = (ushortT*)(ws);
  ushortT* qT   = (ushortT*)(ws + 67108864);
  ushortT* Wqbf = (ushortT*)(ws + 134217728);
  ushortT* Wobf = (ushortT*)(ws + 135790592);
  float*   ct   = (float*)(ws + 136314880);
  float* stats  = (float*)(ws + 138412032);
  float* ksum   = (float*)(ws);                 // aliases xT; written after xT dead
  ushortT* W2   = (ushortT*)(ws + 1048576);     // aliases xT+1MB; written after xT dead
  ushortT* kv   = (ushortT*)d_out;

  cvt_f32_bf16<<<768, 256, 0, stream>>>(Wqkv, Wqbf, 196608);
  cvt_f32_bf16<<<256, 256, 0, stream>>>(Wout, Wobf, 65536);
  zero_f32<<<513, 256, 0, stream>>>(ct, 131080);   // ct + stats

  transpose_x<<<dim3(64, 8, 16), 256, 0, stream>>>(x, xT);

  // kv[b][o'][t] = W_qkv[512+o'][:] . xT[b][t][:]; k-rows (o'<512) exp'd
  gemm_bt<4><<<dim3(32, 8, 16), 256, 0, stream>>>(
      Wqbf + 512 * 512, xT, kv, nullptr, nullptr, 512, 512, 512, 4096,
      0ULL, (unsigned long long)(T_ * 512), (unsigned long long)(1024 * T_));

  // qT[b][t][o] = xT[b][t][:] . W_qkv[o][:]  + fused softmax over d (*SCALE)
  gemm_bt<2><<<dim3(4, 32, 16), 256, 0, stream>>>(
      xT, Wqbf, qT, nullptr, nullptr, 512, 512, 512, 512,
      (unsigned long long)(T_ * 512), 0ULL, (unsigned long long)(T_ * 512));

  // xT dead -> zero ksum (32 KB at ws[0:32K])
  zero_f32<<<8, 256, 0, stream>>>(ksum, 2048);

  context_kv<<<dim3(16, 8, 16), 64, 0, stream>>>(kv, ksum, ct);

  // W2[b] = Wout . (ct[b] * diag(1/ksum))
  ct_combine<<<dim3(8, 8, 16), 64, 0, stream>>>(Wobf, ct, ksum, W2);

  // out[b][c][t] = W2[b][c][:] . qT[b][t][:] + b_out[c], fused GN stats
  gemm_bt<3><<<dim3(32, 4, 16), 256, 0, stream>>>(
      W2, qT, out, bout, stats, 512, 512, 512, 4096,
      (unsigned long long)(512 * 512), (unsigned long long)(T_ * 512),
      (unsigned long long)(512 * T_));

  gn_apply<<<dim3(1024, 16), 256, 0, stream>>>(out, stats, gnw, gnb);
}